// Round 3
// baseline (17009.612 us; speedup 1.0000x reference)
//
#include <hip/hip_runtime.h>
#include <hip/hip_bf16.h>

typedef __attribute__((ext_vector_type(8))) short bf16x8;   // MFMA A/B frag (16B)
typedef __attribute__((ext_vector_type(4))) float f32x4;    // MFMA C/D frag
using bf16 = __hip_bfloat16;

constexpr int BB = 64, TT = 256, DIN = 512, HH = 1024, DOUT = 512;
constexpr int P0 = 1544;   // LDS pitch for W0 rows (1536 + 8)
constexpr int P1 = 2056;   // LDS pitch for W1 rows (2048 + 8)

#define MFMA16(a, b, c) __builtin_amdgcn_mfma_f32_16x16x32_bf16((a), (b), (c), 0, 0, 0)

__device__ __forceinline__ short f2b(float f) {
  __hip_bfloat16 h = __float2bfloat16(f);           // RNE
  return *reinterpret_cast<short*>(&h);
}
// load 8 consecutive fp32, convert to bf16x8 MFMA fragment
__device__ __forceinline__ bf16x8 cvt8(const float* __restrict__ p) {
  const float4 a = *(const float4*)p;
  const float4 b = *(const float4*)(p + 4);
  bf16x8 r;
  r[0] = f2b(a.x); r[1] = f2b(a.y); r[2] = f2b(a.z); r[3] = f2b(a.w);
  r[4] = f2b(b.x); r[5] = f2b(b.y); r[6] = f2b(b.z); r[7] = f2b(b.w);
  return r;
}

// ---------------- global software barrier (monotonic counter) ----------------
__device__ __forceinline__ void bar_arrive(unsigned* bar) {
  __threadfence();                 // release: publish h/c writes at agent scope
  __syncthreads();                 // all threads of block done + fenced
  if (threadIdx.x == 0)
    __hip_atomic_fetch_add(bar, 1u, __ATOMIC_RELAXED, __HIP_MEMORY_SCOPE_AGENT);
}
__device__ __forceinline__ void bar_wait(unsigned* bar, unsigned target) {
  if (threadIdx.x == 0) {
    while (__hip_atomic_load(bar, __ATOMIC_RELAXED, __HIP_MEMORY_SCOPE_AGENT) < target)
      __builtin_amdgcn_s_sleep(1);
  }
  __syncthreads();
  __threadfence();                 // acquire
}

// ---------------- LSTM gate update for one (row, hcol) ----------------
__device__ __forceinline__ void cell(const float zv[4], const float* __restrict__ bias,
                                     float scale, float* __restrict__ cst,
                                     bf16* __restrict__ hdst, int mg, int hcol, bool first) {
  float zf = (zv[0] + bias[0 * HH + hcol]) * scale;
  float zi = (zv[1] + bias[1 * HH + hcol]) * scale;
  float zo = (zv[2] + bias[2 * HH + hcol]) * scale;
  float zg = (zv[3] + bias[3 * HH + hcol]) * scale;
  float f = 1.0f / (1.0f + __expf(-zf));
  float i = 1.0f / (1.0f + __expf(-zi));
  float o = 1.0f / (1.0f + __expf(-zo));
  float g = tanhf(zg);
  float cprev = first ? 0.0f : cst[mg * HH + hcol];
  float cn = f * cprev + i * g;
  cst[mg * HH + hcol] = cn;
  hdst[mg * HH + hcol] = __float2bfloat16(o * tanhf(cn));
}

// ---------------- persistent kernel: 256 blocks x 256 threads, 1 block/CU ----------------
// Block wg owns h-columns [4wg, 4wg+4) of both layers -> its 16 z-cols (z-col n:
// gate = n>>2, hcol = wg*4 + (n&3)). Waves split K (quarter each), block-reduce z via LDS.
// MFMA 16x16x32: A[m=lane&15][k=oct*8+j], D row=oct*4+reg, col=lane&15 (m89-verified).
__global__ void __launch_bounds__(256, 1)
lstm_persist(const float* __restrict__ x,  const float* __restrict__ W0,
             const float* __restrict__ b0, const float* __restrict__ W1,
             const float* __restrict__ b1, const float* __restrict__ Wfc,
             const float* __restrict__ bfc,
             float* __restrict__ c0, float* __restrict__ c1,
             bf16* __restrict__ h0, bf16* __restrict__ h1,
             unsigned* __restrict__ bar, float* __restrict__ out) {
  __shared__ unsigned short lw0[16 * P0];            // 49.4 KB  W0^T cols (this block), bf16
  __shared__ unsigned short lw1[16 * P1];            // 65.8 KB  W1^T cols (this block), bf16
  __shared__ float zbuf[4][4][16][17];               // 17.4 KB  cross-wave z partials

  const int tid  = threadIdx.x;
  const int wg   = blockIdx.x;
  const int lane = tid & 63;
  const int v    = tid >> 6;          // wave id = K-quarter
  const int n    = lane & 15;         // MFMA col / A row-within-tile
  const int oct  = lane >> 4;         // k-octet
  const int mg   = tid & 63;          // epilogue: batch row
  const int hq   = tid >> 6;          // epilogue: hcol offset 0..3
  const int hcol = wg * 4 + hq;
  const float S0 = 1.0f / sqrtf((float)(DIN + HH));
  const float S1 = 1.0f / sqrtf((float)(HH + HH));

  // ---- stage this block's 16 columns of W0/W1 into LDS (fp32 -> bf16, transposed) ----
  {
    const int g = tid >> 6, kw = tid & 63;
    const int col0 = g * HH + wg * 4;                // 4 consecutive cols per gate
    for (int k = kw; k < DIN + HH; k += 64) {
      float4 u = *(const float4*)(W0 + (size_t)k * 4096 + col0);
      lw0[(g * 4 + 0) * P0 + k] = (unsigned short)f2b(u.x);
      lw0[(g * 4 + 1) * P0 + k] = (unsigned short)f2b(u.y);
      lw0[(g * 4 + 2) * P0 + k] = (unsigned short)f2b(u.z);
      lw0[(g * 4 + 3) * P0 + k] = (unsigned short)f2b(u.w);
    }
    for (int k = kw; k < 2 * HH; k += 64) {
      float4 u = *(const float4*)(W1 + (size_t)k * 4096 + col0);
      lw1[(g * 4 + 0) * P1 + k] = (unsigned short)f2b(u.x);
      lw1[(g * 4 + 1) * P1 + k] = (unsigned short)f2b(u.y);
      lw1[(g * 4 + 2) * P1 + k] = (unsigned short)f2b(u.z);
      lw1[(g * 4 + 3) * P1 + k] = (unsigned short)f2b(u.w);
    }
  }
  __syncthreads();

  f32x4 z0a[4], z1a[4];
  float zv[4];

  // =================== window 0: layer0(0), x-part only ===================
#pragma unroll
  for (int rt = 0; rt < 4; ++rt) z0a[rt] = (f32x4){0.f, 0.f, 0.f, 0.f};
#pragma unroll
  for (int s = 0; s < 4; ++s) {
    const int kp = v * 128 + s * 32 + oct * 8;
    bf16x8 bw = *(const bf16x8*)&lw0[n * P0 + kp];
#pragma unroll
    for (int rt = 0; rt < 4; ++rt) {
      bf16x8 a = cvt8(x + ((size_t)(rt * 16 + n) * TT + 0) * DIN + kp);
      z0a[rt] = MFMA16(a, bw, z0a[rt]);
    }
  }
#pragma unroll
  for (int rt = 0; rt < 4; ++rt)
#pragma unroll
    for (int r = 0; r < 4; ++r) zbuf[v][rt][oct * 4 + r][n] = z0a[rt][r];
  __syncthreads();
#pragma unroll
  for (int g = 0; g < 4; ++g)
    zv[g] = zbuf[0][mg >> 4][mg & 15][g * 4 + hq] + zbuf[1][mg >> 4][mg & 15][g * 4 + hq] +
            zbuf[2][mg >> 4][mg & 15][g * 4 + hq] + zbuf[3][mg >> 4][mg & 15][g * 4 + hq];
  cell(zv, b0, S0, c0, h0 /*buf0*/, mg, hcol, true);
  bar_arrive(bar);

  // =================== windows 1..255: layer1(t-1) + layer0(t) ===================
  for (int t = 1; t < TT; ++t) {
    // ---- x-part of layer0(t): no recurrent dependency, hides barrier latency ----
#pragma unroll
    for (int rt = 0; rt < 4; ++rt) z0a[rt] = (f32x4){0.f, 0.f, 0.f, 0.f};
#pragma unroll
    for (int s = 0; s < 4; ++s) {
      const int kp = v * 128 + s * 32 + oct * 8;
      bf16x8 bw = *(const bf16x8*)&lw0[n * P0 + kp];
#pragma unroll
      for (int rt = 0; rt < 4; ++rt) {
        bf16x8 a = cvt8(x + ((size_t)(rt * 16 + n) * TT + t) * DIN + kp);
        z0a[rt] = MFMA16(a, bw, z0a[rt]);
      }
    }

    bar_wait(bar, (unsigned)t * 256u);   // h0(t-1), h1(t-2) now visible

    const bf16* h0p = h0 + ((t - 1) & 1) * (BB * HH);   // h0(t-1)
    const bf16* h1p = h1 + (t & 1) * (BB * HH);         // h1(t-2)
#pragma unroll
    for (int rt = 0; rt < 4; ++rt) z1a[rt] = (f32x4){0.f, 0.f, 0.f, 0.f};

    // ---- shared h0 segment: feeds layer0 (W0 k=512+kp) and layer1 (W1 k=kp) ----
#pragma unroll 2
    for (int s = 0; s < 8; ++s) {
      const int kp = v * 256 + s * 32 + oct * 8;
      bf16x8 bw0 = *(const bf16x8*)&lw0[n * P0 + 512 + kp];
      bf16x8 bw1 = *(const bf16x8*)&lw1[n * P1 + kp];
      bf16x8 a0 = *(const bf16x8*)(h0p + (size_t)(0 * 16 + n) * HH + kp);
      bf16x8 a1 = *(const bf16x8*)(h0p + (size_t)(1 * 16 + n) * HH + kp);
      bf16x8 a2 = *(const bf16x8*)(h0p + (size_t)(2 * 16 + n) * HH + kp);
      bf16x8 a3 = *(const bf16x8*)(h0p + (size_t)(3 * 16 + n) * HH + kp);
      z0a[0] = MFMA16(a0, bw0, z0a[0]);  z1a[0] = MFMA16(a0, bw1, z1a[0]);
      z0a[1] = MFMA16(a1, bw0, z0a[1]);  z1a[1] = MFMA16(a1, bw1, z1a[1]);
      z0a[2] = MFMA16(a2, bw0, z0a[2]);  z1a[2] = MFMA16(a2, bw1, z1a[2]);
      z0a[3] = MFMA16(a3, bw0, z0a[3]);  z1a[3] = MFMA16(a3, bw1, z1a[3]);
    }
    // ---- h1 segment of layer1(t-1): W1 k = 1024 + kp ----
    if (t >= 2) {
#pragma unroll 2
      for (int s = 0; s < 8; ++s) {
        const int kp = v * 256 + s * 32 + oct * 8;
        bf16x8 bw = *(const bf16x8*)&lw1[n * P1 + 1024 + kp];
#pragma unroll
        for (int rt = 0; rt < 4; ++rt) {
          bf16x8 a = *(const bf16x8*)(h1p + (size_t)(rt * 16 + n) * HH + kp);
          z1a[rt] = MFMA16(a, bw, z1a[rt]);
        }
      }
    }

    // ---- reduce z1 across waves -> cell1 -> h1(t-1) ----
#pragma unroll
    for (int rt = 0; rt < 4; ++rt)
#pragma unroll
      for (int r = 0; r < 4; ++r) zbuf[v][rt][oct * 4 + r][n] = z1a[rt][r];
    __syncthreads();
#pragma unroll
    for (int g = 0; g < 4; ++g)
      zv[g] = zbuf[0][mg >> 4][mg & 15][g * 4 + hq] + zbuf[1][mg >> 4][mg & 15][g * 4 + hq] +
              zbuf[2][mg >> 4][mg & 15][g * 4 + hq] + zbuf[3][mg >> 4][mg & 15][g * 4 + hq];
    cell(zv, b1, S1, c1, h1 + ((t - 1) & 1) * (BB * HH), mg, hcol, t == 1);
    __syncthreads();                                    // zbuf reuse
    // ---- reduce z0 across waves -> cell0 -> h0(t) ----
#pragma unroll
    for (int rt = 0; rt < 4; ++rt)
#pragma unroll
      for (int r = 0; r < 4; ++r) zbuf[v][rt][oct * 4 + r][n] = z0a[rt][r];
    __syncthreads();
#pragma unroll
    for (int g = 0; g < 4; ++g)
      zv[g] = zbuf[0][mg >> 4][mg & 15][g * 4 + hq] + zbuf[1][mg >> 4][mg & 15][g * 4 + hq] +
              zbuf[2][mg >> 4][mg & 15][g * 4 + hq] + zbuf[3][mg >> 4][mg & 15][g * 4 + hq];
    cell(zv, b0, S0, c0, h0 + (t & 1) * (BB * HH), mg, hcol, false);
    bar_arrive(bar);
  }

  // =================== final: layer1(255) ===================
  bar_wait(bar, 256u * 256u);
  {
    const bf16* h0p = h0 + 1 * (BB * HH);   // h0(255)
    const bf16* h1p = h1 + 0 * (BB * HH);   // h1(254)
#pragma unroll
    for (int rt = 0; rt < 4; ++rt) z1a[rt] = (f32x4){0.f, 0.f, 0.f, 0.f};
#pragma unroll 2
    for (int s = 0; s < 8; ++s) {
      const int kp = v * 256 + s * 32 + oct * 8;
      bf16x8 bw1 = *(const bf16x8*)&lw1[n * P1 + kp];
      bf16x8 bw2 = *(const bf16x8*)&lw1[n * P1 + 1024 + kp];
#pragma unroll
      for (int rt = 0; rt < 4; ++rt) {
        bf16x8 a = *(const bf16x8*)(h0p + (size_t)(rt * 16 + n) * HH + kp);
        z1a[rt] = MFMA16(a, bw1, z1a[rt]);
      }
#pragma unroll
      for (int rt = 0; rt < 4; ++rt) {
        bf16x8 a = *(const bf16x8*)(h1p + (size_t)(rt * 16 + n) * HH + kp);
        z1a[rt] = MFMA16(a, bw2, z1a[rt]);
      }
    }
#pragma unroll
    for (int rt = 0; rt < 4; ++rt)
#pragma unroll
      for (int r = 0; r < 4; ++r) zbuf[v][rt][oct * 4 + r][n] = z1a[rt][r];
    __syncthreads();
#pragma unroll
    for (int g = 0; g < 4; ++g)
      zv[g] = zbuf[0][mg >> 4][mg & 15][g * 4 + hq] + zbuf[1][mg >> 4][mg & 15][g * 4 + hq] +
              zbuf[2][mg >> 4][mg & 15][g * 4 + hq] + zbuf[3][mg >> 4][mg & 15][g * 4 + hq];
    cell(zv, b1, S1, c1, h1 + 1 * (BB * HH), mg, hcol, false);   // h1(255) -> buf1
  }
  bar_arrive(bar);

  // ============ final FC: out = h1(255) @ Wfc + bfc (blocks 0..31) ============
  if (wg < DOUT / 16) {
    bar_wait(bar, 257u * 256u);
    {  // stage Wfc cols [wg*16, wg*16+16) into lw0 region (fp32 -> bf16)
      const int q = tid >> 6, kw = tid & 63;
      for (int k = kw; k < HH; k += 64) {
        float4 u = *(const float4*)(Wfc + (size_t)k * DOUT + wg * 16 + q * 4);
        lw0[(q * 4 + 0) * P0 + k] = (unsigned short)f2b(u.x);
        lw0[(q * 4 + 1) * P0 + k] = (unsigned short)f2b(u.y);
        lw0[(q * 4 + 2) * P0 + k] = (unsigned short)f2b(u.z);
        lw0[(q * 4 + 3) * P0 + k] = (unsigned short)f2b(u.w);
      }
    }
    __syncthreads();
    const bf16* h1f = h1 + 1 * (BB * HH);   // h1(255)
    f32x4 acc0 = {0.f, 0.f, 0.f, 0.f}, acc1 = {0.f, 0.f, 0.f, 0.f};
#pragma unroll 4
    for (int k = 0; k < HH; k += 64) {
      bf16x8 bwA = *(const bf16x8*)&lw0[n * P0 + k + oct * 8];
      bf16x8 aA  = *(const bf16x8*)(h1f + (size_t)(v * 16 + n) * HH + k + oct * 8);
      acc0 = MFMA16(aA, bwA, acc0);
      bf16x8 bwB = *(const bf16x8*)&lw0[n * P0 + k + 32 + oct * 8];
      bf16x8 aB  = *(const bf16x8*)(h1f + (size_t)(v * 16 + n) * HH + k + 32 + oct * 8);
      acc1 = MFMA16(aB, bwB, acc1);
    }
    float bb = bfc[wg * 16 + n];
#pragma unroll
    for (int r = 0; r < 4; ++r) {
      int row = v * 16 + oct * 4 + r;
      out[(size_t)row * DOUT + wg * 16 + n] = acc0[r] + acc1[r] + bb;
    }
  }
}

extern "C" void kernel_launch(void* const* d_in, const int* in_sizes, int n_in,
                              void* d_out, int out_size, void* d_ws, size_t ws_size,
                              hipStream_t stream) {
  const float* x   = (const float*)d_in[0];
  const float* W0  = (const float*)d_in[1];
  const float* b0  = (const float*)d_in[2];
  const float* W1  = (const float*)d_in[3];
  const float* b1  = (const float*)d_in[4];
  const float* Wfc = (const float*)d_in[5];
  const float* bfc = (const float*)d_in[6];

  // ---- workspace (~1.3 MB): barrier counter + states ----
  char* ws = (char*)d_ws;
  size_t off = 0;
  unsigned* bar = (unsigned*)(ws + off); off += 256;                      // counter (padded)
  float* c0 = (float*)(ws + off); off += (size_t)BB * HH * 4;             // fp32 cell state L0
  float* c1 = (float*)(ws + off); off += (size_t)BB * HH * 4;             // fp32 cell state L1
  bf16*  h0 = (bf16*)(ws + off);  off += (size_t)2 * BB * HH * 2;         // h0 double-buffer
  bf16*  h1 = (bf16*)(ws + off);  off += (size_t)2 * BB * HH * 2;         // h1 double-buffer

  hipMemsetAsync(bar, 0, 256, stream);   // ws re-poisoned each call; counter must start at 0

  lstm_persist<<<dim3(256), dim3(256), 0, stream>>>(
      x, W0, b0, W1, b1, Wfc, bfc, c0, c1, h0, h1, bar, (float*)d_out);
}

// Round 4
// 5430.517 us; speedup vs baseline: 3.1322x; 3.1322x over previous
//
#include <hip/hip_runtime.h>
#include <hip/hip_bf16.h>

typedef __attribute__((ext_vector_type(8))) short bf16x8;   // MFMA A/B frag (16B)
typedef __attribute__((ext_vector_type(4))) float f32x4;    // MFMA C/D frag
using bf16 = __hip_bfloat16;
typedef unsigned long long u64;

constexpr int BB = 64, TT = 256, DIN = 512, HH = 1024, DOUT = 512;
constexpr int P0 = 1544;   // LDS pitch for W0 rows (1536 + 8)
constexpr int P1 = 2056;   // LDS pitch for W1 rows (2048 + 8)

#define MFMA16(a, b, c) __builtin_amdgcn_mfma_f32_16x16x32_bf16((a), (b), (c), 0, 0, 0)

__device__ __forceinline__ short f2b(float f) {
  __hip_bfloat16 h = __float2bfloat16(f);           // RNE
  return *reinterpret_cast<short*>(&h);
}
__device__ __forceinline__ bf16x8 cvt8(const float* __restrict__ p) {
  const float4 a = *(const float4*)p;
  const float4 b = *(const float4*)(p + 4);
  bf16x8 r;
  r[0] = f2b(a.x); r[1] = f2b(a.y); r[2] = f2b(a.z); r[3] = f2b(a.w);
  r[4] = f2b(b.x); r[5] = f2b(b.y); r[6] = f2b(b.z); r[7] = f2b(b.w);
  return r;
}

// gate math: z -> (h bf16 bits), updates c register
__device__ __forceinline__ unsigned short gates(const float zv[4], const float br[4],
                                                float scale, float& cr, bool first) {
  float zf = (zv[0] + br[0]) * scale;
  float zi = (zv[1] + br[1]) * scale;
  float zo = (zv[2] + br[2]) * scale;
  float zg = (zv[3] + br[3]) * scale;
  float f = 1.0f / (1.0f + __expf(-zf));
  float i = 1.0f / (1.0f + __expf(-zi));
  float o = 1.0f / (1.0f + __expf(-zo));
  float g = tanhf(zg);
  float cn = f * (first ? 0.0f : cr) + i * g;
  cr = cn;
  __hip_bfloat16 hv = __float2bfloat16(o * tanhf(cn));
  return *reinterpret_cast<unsigned short*>(&hv);
}

// ---------------- persistent kernel: 256 blocks x 256 threads, 1 block/CU ----------------
// Block wg owns h-cols [4wg,4wg+4) of both layers -> its 16 z-cols (gate=n>>2, hcol=wg*4+(n&3)).
// Waves split K; block-reduce z via LDS. No dirty L2 lines in steady state: c in registers,
// h published via agent-scope (sc1, write-through) 8B atomic stores. Barrier = per-block flag
// array (no RMW); release = s_waitcnt + flag store; acquire = agent fence (buffer_inv only).
__global__ void __launch_bounds__(256, 1)
lstm_persist(const float* __restrict__ x,  const float* __restrict__ W0,
             const float* __restrict__ b0, const float* __restrict__ W1,
             const float* __restrict__ b1, const float* __restrict__ Wfc,
             const float* __restrict__ bfc,
             bf16* __restrict__ h0, bf16* __restrict__ h1,
             unsigned* __restrict__ flags, float* __restrict__ out) {
  __shared__ unsigned short lw0[16 * P0];            // 49.4 KB  W0^T cols (this block), bf16
  __shared__ unsigned short lw1[16 * P1];            // 65.8 KB  W1^T cols (this block), bf16
  __shared__ float zbuf[4][4][16][17];               // 17.4 KB  cross-wave z partials
  __shared__ unsigned short hs[64][4];               // 0.5 KB   h-tile staging for publish

  const int tid  = threadIdx.x;
  const int wg   = blockIdx.x;
  const int lane = tid & 63;
  const int v    = tid >> 6;          // wave id = K-quarter
  const int n    = lane & 15;         // MFMA col / A row-within-tile
  const int oct  = lane >> 4;         // k-octet
  const int mg   = tid & 63;          // epilogue: batch row
  const int hq   = tid >> 6;          // epilogue: hcol offset 0..3
  const int hcol = wg * 4 + hq;
  const float S0 = 1.0f / sqrtf((float)(DIN + HH));
  const float S1 = 1.0f / sqrtf((float)(HH + HH));

  // per-thread recurrent state + biases in registers (never exchanged)
  float c0r = 0.0f, c1r = 0.0f;
  float b0r[4], b1r[4];
#pragma unroll
  for (int g = 0; g < 4; ++g) { b0r[g] = b0[g * HH + hcol]; b1r[g] = b1[g * HH + hcol]; }

  // ---- stage this block's 16 columns of W0/W1 into LDS (fp32 -> bf16, transposed) ----
  {
    const int g = tid >> 6, kw = tid & 63;
    const int col0 = g * HH + wg * 4;
    for (int k = kw; k < DIN + HH; k += 64) {
      float4 u = *(const float4*)(W0 + (size_t)k * 4096 + col0);
      lw0[(g * 4 + 0) * P0 + k] = (unsigned short)f2b(u.x);
      lw0[(g * 4 + 1) * P0 + k] = (unsigned short)f2b(u.y);
      lw0[(g * 4 + 2) * P0 + k] = (unsigned short)f2b(u.z);
      lw0[(g * 4 + 3) * P0 + k] = (unsigned short)f2b(u.w);
    }
    for (int k = kw; k < 2 * HH; k += 64) {
      float4 u = *(const float4*)(W1 + (size_t)k * 4096 + col0);
      lw1[(g * 4 + 0) * P1 + k] = (unsigned short)f2b(u.x);
      lw1[(g * 4 + 1) * P1 + k] = (unsigned short)f2b(u.y);
      lw1[(g * 4 + 2) * P1 + k] = (unsigned short)f2b(u.z);
      lw1[(g * 4 + 3) * P1 + k] = (unsigned short)f2b(u.w);
    }
  }
  __syncthreads();

  f32x4 z0a[4], z1a[4];
  float zv[4];

  // publish: wave 0 stores 64 rows x 8B (4 bf16) write-through at agent scope
  auto publish = [&](bf16* dst) {
    if (tid < 64) {
      u64 val = *(const u64*)&hs[tid][0];
      __hip_atomic_store((u64*)(dst + (size_t)tid * HH + wg * 4), val,
                         __ATOMIC_RELAXED, __HIP_MEMORY_SCOPE_AGENT);
    }
  };
  auto flag_release = [&](unsigned val) {
    if (tid < 64) __builtin_amdgcn_s_waitcnt(0);     // wave0: drain sc1 h stores
    if (tid == 0)
      __hip_atomic_store(&flags[wg], val, __ATOMIC_RELAXED, __HIP_MEMORY_SCOPE_AGENT);
  };
  auto bar_wait = [&](unsigned target) {
    while (__hip_atomic_load(&flags[tid], __ATOMIC_RELAXED, __HIP_MEMORY_SCOPE_AGENT) < target)
      __builtin_amdgcn_s_sleep(1);
    __syncthreads();
    __builtin_amdgcn_fence(__ATOMIC_ACQUIRE, "agent");   // buffer_inv: drop stale L2 h lines
  };

  // =================== window 0: layer0(0), x-part only ===================
#pragma unroll
  for (int rt = 0; rt < 4; ++rt) z0a[rt] = (f32x4){0.f, 0.f, 0.f, 0.f};
#pragma unroll
  for (int s = 0; s < 4; ++s) {
    const int kp = v * 128 + s * 32 + oct * 8;
    bf16x8 bw = *(const bf16x8*)&lw0[n * P0 + kp];
#pragma unroll
    for (int rt = 0; rt < 4; ++rt) {
      bf16x8 a = cvt8(x + ((size_t)(rt * 16 + n) * TT + 0) * DIN + kp);
      z0a[rt] = MFMA16(a, bw, z0a[rt]);
    }
  }
#pragma unroll
  for (int rt = 0; rt < 4; ++rt)
#pragma unroll
    for (int r = 0; r < 4; ++r) zbuf[v][rt][oct * 4 + r][n] = z0a[rt][r];
  __syncthreads();
#pragma unroll
  for (int g = 0; g < 4; ++g)
    zv[g] = zbuf[0][mg >> 4][mg & 15][g * 4 + hq] + zbuf[1][mg >> 4][mg & 15][g * 4 + hq] +
            zbuf[2][mg >> 4][mg & 15][g * 4 + hq] + zbuf[3][mg >> 4][mg & 15][g * 4 + hq];
  hs[mg][hq] = gates(zv, b0r, S0, c0r, true);
  __syncthreads();
  publish(h0 /*buf0*/);
  flag_release(1u);

  // =================== windows 1..255: layer1(t-1) + layer0(t) ===================
  for (int t = 1; t < TT; ++t) {
    // ---- x-part of layer0(t): no recurrent dependency, hides barrier latency ----
#pragma unroll
    for (int rt = 0; rt < 4; ++rt) z0a[rt] = (f32x4){0.f, 0.f, 0.f, 0.f};
#pragma unroll
    for (int s = 0; s < 4; ++s) {
      const int kp = v * 128 + s * 32 + oct * 8;
      bf16x8 bw = *(const bf16x8*)&lw0[n * P0 + kp];
#pragma unroll
      for (int rt = 0; rt < 4; ++rt) {
        bf16x8 a = cvt8(x + ((size_t)(rt * 16 + n) * TT + t) * DIN + kp);
        z0a[rt] = MFMA16(a, bw, z0a[rt]);
      }
    }

    bar_wait((unsigned)t);   // all blocks finished window t-1: h0(t-1), h1(t-2) visible

    const bf16* h0p = h0 + ((t - 1) & 1) * (BB * HH);   // h0(t-1)
    const bf16* h1p = h1 + (t & 1) * (BB * HH);         // h1(t-2)
#pragma unroll
    for (int rt = 0; rt < 4; ++rt) z1a[rt] = (f32x4){0.f, 0.f, 0.f, 0.f};

    // ---- shared h0 segment: feeds layer0 (W0 k=512+kp) and layer1 (W1 k=kp) ----
#pragma unroll 2
    for (int s = 0; s < 8; ++s) {
      const int kp = v * 256 + s * 32 + oct * 8;
      bf16x8 bw0 = *(const bf16x8*)&lw0[n * P0 + 512 + kp];
      bf16x8 bw1 = *(const bf16x8*)&lw1[n * P1 + kp];
      bf16x8 a0 = *(const bf16x8*)(h0p + (size_t)(0 * 16 + n) * HH + kp);
      bf16x8 a1 = *(const bf16x8*)(h0p + (size_t)(1 * 16 + n) * HH + kp);
      bf16x8 a2 = *(const bf16x8*)(h0p + (size_t)(2 * 16 + n) * HH + kp);
      bf16x8 a3 = *(const bf16x8*)(h0p + (size_t)(3 * 16 + n) * HH + kp);
      z0a[0] = MFMA16(a0, bw0, z0a[0]);  z1a[0] = MFMA16(a0, bw1, z1a[0]);
      z0a[1] = MFMA16(a1, bw0, z0a[1]);  z1a[1] = MFMA16(a1, bw1, z1a[1]);
      z0a[2] = MFMA16(a2, bw0, z0a[2]);  z1a[2] = MFMA16(a2, bw1, z1a[2]);
      z0a[3] = MFMA16(a3, bw0, z0a[3]);  z1a[3] = MFMA16(a3, bw1, z1a[3]);
    }
    // ---- h1 segment of layer1(t-1): W1 k = 1024 + kp ----
    if (t >= 2) {
#pragma unroll 2
      for (int s = 0; s < 8; ++s) {
        const int kp = v * 256 + s * 32 + oct * 8;
        bf16x8 bw = *(const bf16x8*)&lw1[n * P1 + 1024 + kp];
#pragma unroll
        for (int rt = 0; rt < 4; ++rt) {
          bf16x8 a = *(const bf16x8*)(h1p + (size_t)(rt * 16 + n) * HH + kp);
          z1a[rt] = MFMA16(a, bw, z1a[rt]);
        }
      }
    }

    // ---- reduce z1 -> cell1 -> publish h1(t-1) ----
#pragma unroll
    for (int rt = 0; rt < 4; ++rt)
#pragma unroll
      for (int r = 0; r < 4; ++r) zbuf[v][rt][oct * 4 + r][n] = z1a[rt][r];
    __syncthreads();
#pragma unroll
    for (int g = 0; g < 4; ++g)
      zv[g] = zbuf[0][mg >> 4][mg & 15][g * 4 + hq] + zbuf[1][mg >> 4][mg & 15][g * 4 + hq] +
              zbuf[2][mg >> 4][mg & 15][g * 4 + hq] + zbuf[3][mg >> 4][mg & 15][g * 4 + hq];
    hs[mg][hq] = gates(zv, b1r, S1, c1r, t == 1);
    __syncthreads();                      // zbuf reads done + hs complete
    publish(h1 + ((t - 1) & 1) * (BB * HH));
    // ---- reduce z0 -> cell0 -> publish h0(t) ----
#pragma unroll
    for (int rt = 0; rt < 4; ++rt)
#pragma unroll
      for (int r = 0; r < 4; ++r) zbuf[v][rt][oct * 4 + r][n] = z0a[rt][r];
    __syncthreads();                      // also: wave0's hs reads (publish) drained
#pragma unroll
    for (int g = 0; g < 4; ++g)
      zv[g] = zbuf[0][mg >> 4][mg & 15][g * 4 + hq] + zbuf[1][mg >> 4][mg & 15][g * 4 + hq] +
              zbuf[2][mg >> 4][mg & 15][g * 4 + hq] + zbuf[3][mg >> 4][mg & 15][g * 4 + hq];
    hs[mg][hq] = gates(zv, b0r, S0, c0r, false);
    __syncthreads();
    publish(h0 + (t & 1) * (BB * HH));
    flag_release((unsigned)t + 1u);
  }

  // =================== final: layer1(255) ===================
  bar_wait(256u);
  {
    const bf16* h0p = h0 + 1 * (BB * HH);   // h0(255)
    const bf16* h1p = h1 + 0 * (BB * HH);   // h1(254)
#pragma unroll
    for (int rt = 0; rt < 4; ++rt) z1a[rt] = (f32x4){0.f, 0.f, 0.f, 0.f};
#pragma unroll 2
    for (int s = 0; s < 8; ++s) {
      const int kp = v * 256 + s * 32 + oct * 8;
      bf16x8 bw1 = *(const bf16x8*)&lw1[n * P1 + kp];
      bf16x8 bw2 = *(const bf16x8*)&lw1[n * P1 + 1024 + kp];
#pragma unroll
      for (int rt = 0; rt < 4; ++rt) {
        bf16x8 a = *(const bf16x8*)(h0p + (size_t)(rt * 16 + n) * HH + kp);
        z1a[rt] = MFMA16(a, bw1, z1a[rt]);
      }
#pragma unroll
      for (int rt = 0; rt < 4; ++rt) {
        bf16x8 a = *(const bf16x8*)(h1p + (size_t)(rt * 16 + n) * HH + kp);
        z1a[rt] = MFMA16(a, bw2, z1a[rt]);
      }
    }
#pragma unroll
    for (int rt = 0; rt < 4; ++rt)
#pragma unroll
      for (int r = 0; r < 4; ++r) zbuf[v][rt][oct * 4 + r][n] = z1a[rt][r];
    __syncthreads();
#pragma unroll
    for (int g = 0; g < 4; ++g)
      zv[g] = zbuf[0][mg >> 4][mg & 15][g * 4 + hq] + zbuf[1][mg >> 4][mg & 15][g * 4 + hq] +
              zbuf[2][mg >> 4][mg & 15][g * 4 + hq] + zbuf[3][mg >> 4][mg & 15][g * 4 + hq];
    hs[mg][hq] = gates(zv, b1r, S1, c1r, false);
    __syncthreads();
    publish(h1 + 1 * (BB * HH));           // h1(255) -> buf1 (h1(253) already consumed)
    flag_release(257u);
  }

  // ============ final FC: out = h1(255) @ Wfc + bfc (blocks 0..31) ============
  if (wg < DOUT / 16) {
    bar_wait(257u);
    {  // stage Wfc cols [wg*16, wg*16+16) into lw0 region (fp32 -> bf16)
      const int q = tid >> 6, kw = tid & 63;
      for (int k = kw; k < HH; k += 64) {
        float4 u = *(const float4*)(Wfc + (size_t)k * DOUT + wg * 16 + q * 4);
        lw0[(q * 4 + 0) * P0 + k] = (unsigned short)f2b(u.x);
        lw0[(q * 4 + 1) * P0 + k] = (unsigned short)f2b(u.y);
        lw0[(q * 4 + 2) * P0 + k] = (unsigned short)f2b(u.z);
        lw0[(q * 4 + 3) * P0 + k] = (unsigned short)f2b(u.w);
      }
    }
    __syncthreads();
    const bf16* h1f = h1 + 1 * (BB * HH);   // h1(255)
    f32x4 acc0 = {0.f, 0.f, 0.f, 0.f}, acc1 = {0.f, 0.f, 0.f, 0.f};
#pragma unroll 4
    for (int k = 0; k < HH; k += 64) {
      bf16x8 bwA = *(const bf16x8*)&lw0[n * P0 + k + oct * 8];
      bf16x8 aA  = *(const bf16x8*)(h1f + (size_t)(v * 16 + n) * HH + k + oct * 8);
      acc0 = MFMA16(aA, bwA, acc0);
      bf16x8 bwB = *(const bf16x8*)&lw0[n * P0 + k + 32 + oct * 8];
      bf16x8 aB  = *(const bf16x8*)(h1f + (size_t)(v * 16 + n) * HH + k + 32 + oct * 8);
      acc1 = MFMA16(aB, bwB, acc1);
    }
    float bb = bfc[wg * 16 + n];
#pragma unroll
    for (int r = 0; r < 4; ++r) {
      int row = v * 16 + oct * 4 + r;
      out[(size_t)row * DOUT + wg * 16 + n] = acc0[r] + acc1[r] + bb;
    }
  }
}

extern "C" void kernel_launch(void* const* d_in, const int* in_sizes, int n_in,
                              void* d_out, int out_size, void* d_ws, size_t ws_size,
                              hipStream_t stream) {
  const float* x   = (const float*)d_in[0];
  const float* W0  = (const float*)d_in[1];
  const float* b0  = (const float*)d_in[2];
  const float* W1  = (const float*)d_in[3];
  const float* b1  = (const float*)d_in[4];
  const float* Wfc = (const float*)d_in[5];
  const float* bfc = (const float*)d_in[6];

  // ---- workspace (~0.5 MB): flag array + h double-buffers ----
  char* ws = (char*)d_ws;
  size_t off = 0;
  unsigned* flags = (unsigned*)(ws + off); off += 4096;                   // 256 flags (1KB used)
  bf16* h0 = (bf16*)(ws + off); off += (size_t)2 * BB * HH * 2;           // h0 double-buffer
  bf16* h1 = (bf16*)(ws + off); off += (size_t)2 * BB * HH * 2;           // h1 double-buffer

  hipMemsetAsync(flags, 0, 4096, stream);   // ws re-poisoned each call; flags must start at 0

  lstm_persist<<<dim3(256), dim3(256), 0, stream>>>(
      x, W0, b0, W1, b1, Wfc, bfc, h0, h1, flags, (float*)d_out);
}